// Round 1
// baseline (195.862 us; speedup 1.0000x reference)
//
#include <hip/hip_runtime.h>

// ---------------- problem constants ----------------
#define N_    8
#define IC_   128
#define OC_   128
#define HW_   68
#define TH_   16
#define TW_   16
#define M_    (N_ * TH_ * TW_)   // 2048 tiles total
#define OW_   64

constexpr float BT[8][8] = {
  {1.f, 0.f, -5.25f, 0.f, 5.25f, 0.f, -1.f, 0.f},
  {0.f, 1.f, 1.f, -4.25f, -4.25f, 1.f, 1.f, 0.f},
  {0.f, -1.f, 1.f, 4.25f, -4.25f, -1.f, 1.f, 0.f},
  {0.f, 0.5f, 0.25f, -2.5f, -1.25f, 2.f, 1.f, 0.f},
  {0.f, -0.5f, 0.25f, 2.5f, -1.25f, -2.f, 1.f, 0.f},
  {0.f, 2.f, 4.f, -2.5f, -5.f, 0.5f, 1.f, 0.f},
  {0.f, -2.f, 4.f, 2.5f, -5.f, -0.5f, 1.f, 0.f},
  {0.f, -1.f, 0.f, 5.25f, 0.f, -5.25f, 0.f, 1.f}
};
constexpr float AT[4][8] = {
  {1.f, 1.f, 1.f, 1.f, 1.f, 8.f, 8.f, 0.f},
  {0.f, 1.f, -1.f, 2.f, -2.f, 4.f, -4.f, 0.f},
  {0.f, 1.f, 1.f, 4.f, 4.f, 2.f, 2.f, 0.f},
  {0.f, 1.f, -1.f, 8.f, -8.f, 1.f, -1.f, 1.f}
};

__device__ __forceinline__ float bf2f(unsigned short u) {
  union { unsigned int i; float f; } v; v.i = ((unsigned int)u) << 16; return v.f;
}
__device__ __forceinline__ unsigned short f2bf(float f) {
  union { float f; unsigned int i; } v; v.f = f;
  unsigned int r = v.i + 0x7FFFu + ((v.i >> 16) & 1u);  // RNE
  return (unsigned short)(r >> 16);
}

// ---------------- K1: input transform ----------------
// block = one tile m (n,th,tw); thread = channel c. xt[ab][m][c] bf16.
__global__ __launch_bounds__(128) void k_input_tf(const float* __restrict__ x,
                                                  unsigned short* __restrict__ xt) {
  const int m = blockIdx.x;
  const int c = threadIdx.x;
  const int n = m >> 8, th = (m >> 4) & 15, tw = m & 15;
  const float* xp = x + (((size_t)(n * IC_ + c) * HW_) + th * 4) * (size_t)HW_ + tw * 4;

  float t1[8][8];
#pragma unroll
  for (int a = 0; a < 8; ++a)
#pragma unroll
    for (int j = 0; j < 8; ++j) t1[a][j] = 0.f;

#pragma unroll
  for (int i = 0; i < 8; ++i) {
    const float4* rp = reinterpret_cast<const float4*>(xp + (size_t)i * HW_);
    float4 v0 = rp[0], v1 = rp[1];
    float r[8] = {v0.x, v0.y, v0.z, v0.w, v1.x, v1.y, v1.z, v1.w};
#pragma unroll
    for (int a = 0; a < 8; ++a) {
      const float ba = BT[a][i];
      if (ba != 0.f) {
#pragma unroll
        for (int j = 0; j < 8; ++j) t1[a][j] += ba * r[j];
      }
    }
  }

  const size_t mbase = (size_t)m * 128 + c;
#pragma unroll
  for (int a = 0; a < 8; ++a) {
#pragma unroll
    for (int b = 0; b < 8; ++b) {
      float v = 0.f;
#pragma unroll
      for (int j = 0; j < 8; ++j) {
        const float bb = BT[b][j];
        if (bb != 0.f) v += t1[a][j] * bb;
      }
      xt[(size_t)(a * 8 + b) * M_ * 128 + mbase] = f2bf(v);
    }
  }
}

// ---------------- K2: weight transpose ----------------
// wT[ab][c][oc] = weight[oc][c][ab]
__global__ __launch_bounds__(256) void k_wt(const float* __restrict__ w,
                                            float* __restrict__ wT) {
  const int idx = blockIdx.x * 256 + threadIdx.x;  // 64*128*128 = 1,048,576
  const int oc = idx & 127;
  const int c  = (idx >> 7) & 127;
  const int ab = idx >> 14;
  wT[idx] = w[((size_t)oc * IC_ + c) * 64 + ab];
}

// ---------------- K3: batched GEMM (fp32 vector, baseline) ----------------
// per ab: C[m][oc] = sum_c A[m][c] * B[c][oc];  A bf16, B f32, C bf16
__global__ __launch_bounds__(256) void k_gemm(const unsigned short* __restrict__ xt,
                                              const float* __restrict__ wT,
                                              unsigned short* __restrict__ yt) {
  const int ab = blockIdx.z;
  const int m0 = blockIdx.x * 64;
  const int n0 = blockIdx.y * 64;
  const unsigned short* Ag = xt + (size_t)ab * M_ * 128;
  const float* Bg = wT + (size_t)ab * 128 * 128;
  unsigned short* Cg = yt + (size_t)ab * M_ * 128;

  __shared__ float As[16][64];
  __shared__ float Bs[16][64];

  const int tid = threadIdx.x;
  const int mf = (tid >> 4) * 4;
  const int nf = (tid & 15) * 4;

  float acc[4][4] = {};

  for (int k0 = 0; k0 < 128; k0 += 16) {
    // stage A: 64 rows x 16 k  (each thread: 4 contiguous bf16 = 8B)
    {
      const int row = tid >> 2;
      const int kk = (tid & 3) * 4;
      const ushort4 av = *reinterpret_cast<const ushort4*>(
          Ag + (size_t)(m0 + row) * 128 + k0 + kk);
      As[kk + 0][row] = bf2f(av.x);
      As[kk + 1][row] = bf2f(av.y);
      As[kk + 2][row] = bf2f(av.z);
      As[kk + 3][row] = bf2f(av.w);
    }
    // stage B: 16 k x 64 oc (each thread: float4)
    {
      const int kb = tid >> 4;
      const int jb = (tid & 15) * 4;
      const float4 bv = *reinterpret_cast<const float4*>(
          Bg + (size_t)(k0 + kb) * 128 + n0 + jb);
      *reinterpret_cast<float4*>(&Bs[kb][jb]) = bv;
    }
    __syncthreads();
#pragma unroll
    for (int kk = 0; kk < 16; ++kk) {
      float a0 = As[kk][mf + 0], a1 = As[kk][mf + 1];
      float a2 = As[kk][mf + 2], a3 = As[kk][mf + 3];
      float b0 = Bs[kk][nf + 0], b1 = Bs[kk][nf + 1];
      float b2 = Bs[kk][nf + 2], b3 = Bs[kk][nf + 3];
      acc[0][0] += a0 * b0; acc[0][1] += a0 * b1; acc[0][2] += a0 * b2; acc[0][3] += a0 * b3;
      acc[1][0] += a1 * b0; acc[1][1] += a1 * b1; acc[1][2] += a1 * b2; acc[1][3] += a1 * b3;
      acc[2][0] += a2 * b0; acc[2][1] += a2 * b1; acc[2][2] += a2 * b2; acc[2][3] += a2 * b3;
      acc[3][0] += a3 * b0; acc[3][1] += a3 * b1; acc[3][2] += a3 * b2; acc[3][3] += a3 * b3;
    }
    __syncthreads();
  }

#pragma unroll
  for (int i = 0; i < 4; ++i)
#pragma unroll
    for (int j = 0; j < 4; ++j)
      Cg[(size_t)(m0 + mf + i) * 128 + n0 + nf + j] = f2bf(acc[i][j]);
}

// ---------------- K4: output transform + bias ----------------
// block = tile m; thread = oc. reads yt[ab][m][oc], writes y[n][oc][4x4 block]
__global__ __launch_bounds__(128) void k_output_tf(const unsigned short* __restrict__ yt,
                                                   const float* __restrict__ bias,
                                                   float* __restrict__ y) {
  const int m = blockIdx.x;
  const int oc = threadIdx.x;
  const int n = m >> 8, th = (m >> 4) & 15, tw = m & 15;

  float Y[8][8];
#pragma unroll
  for (int a = 0; a < 8; ++a)
#pragma unroll
    for (int b = 0; b < 8; ++b)
      Y[a][b] = bf2f(yt[(size_t)(a * 8 + b) * M_ * 128 + (size_t)m * 128 + oc]);

  float t2[4][8];
#pragma unroll
  for (int p = 0; p < 4; ++p)
#pragma unroll
    for (int b = 0; b < 8; ++b) {
      float v = 0.f;
#pragma unroll
      for (int a = 0; a < 8; ++a) {
        const float aa = AT[p][a];
        if (aa != 0.f) v += aa * Y[a][b];
      }
      t2[p][b] = v;
    }

  const float bv = bias[oc];
  float* yp = y + (((size_t)(n * OC_ + oc) * OW_) + th * 4) * (size_t)OW_ + tw * 4;
#pragma unroll
  for (int p = 0; p < 4; ++p) {
    float o[4];
#pragma unroll
    for (int q = 0; q < 4; ++q) {
      float v = 0.f;
#pragma unroll
      for (int b = 0; b < 8; ++b) {
        const float ab_ = AT[q][b];
        if (ab_ != 0.f) v += t2[p][b] * ab_;
      }
      o[q] = v + bv;
    }
    float4 ov = {o[0], o[1], o[2], o[3]};
    *reinterpret_cast<float4*>(yp + (size_t)p * OW_) = ov;
  }
}

// ---------------- launch ----------------
extern "C" void kernel_launch(void* const* d_in, const int* in_sizes, int n_in,
                              void* d_out, int out_size, void* d_ws, size_t ws_size,
                              hipStream_t stream) {
  (void)in_sizes; (void)n_in; (void)out_size; (void)ws_size;
  const float* x    = (const float*)d_in[0];
  const float* w    = (const float*)d_in[1];
  const float* bias = (const float*)d_in[2];
  float* y = (float*)d_out;

  char* ws = (char*)d_ws;
  unsigned short* xt = (unsigned short*)ws;                                   // 32 MiB
  unsigned short* yt = (unsigned short*)(ws + (size_t)32 * 1024 * 1024);      // 32 MiB
  float* wT          = (float*)(ws + (size_t)64 * 1024 * 1024);               //  4 MiB

  hipLaunchKernelGGL(k_input_tf, dim3(M_), dim3(128), 0, stream, x, xt);
  hipLaunchKernelGGL(k_wt, dim3((64 * 128 * 128) / 256), dim3(256), 0, stream, w, wT);
  hipLaunchKernelGGL(k_gemm, dim3(32, 2, 64), dim3(256), 0, stream, xt, wT, yt);
  hipLaunchKernelGGL(k_output_tf, dim3(M_), dim3(128), 0, stream, yt, bias, y);
}

// Round 2
// 120.672 us; speedup vs baseline: 1.6231x; 1.6231x over previous
//
#include <hip/hip_runtime.h>

// ---------------- problem constants ----------------
#define N_    8
#define IC_   128
#define OC_   128
#define HW_   68
#define M_    2048           // total tiles = 8 * 16 * 16
#define OW_   64

constexpr float BT[8][8] = {
  {1.f, 0.f, -5.25f, 0.f, 5.25f, 0.f, -1.f, 0.f},
  {0.f, 1.f, 1.f, -4.25f, -4.25f, 1.f, 1.f, 0.f},
  {0.f, -1.f, 1.f, 4.25f, -4.25f, -1.f, 1.f, 0.f},
  {0.f, 0.5f, 0.25f, -2.5f, -1.25f, 2.f, 1.f, 0.f},
  {0.f, -0.5f, 0.25f, 2.5f, -1.25f, -2.f, 1.f, 0.f},
  {0.f, 2.f, 4.f, -2.5f, -5.f, 0.5f, 1.f, 0.f},
  {0.f, -2.f, 4.f, 2.5f, -5.f, -0.5f, 1.f, 0.f},
  {0.f, -1.f, 0.f, 5.25f, 0.f, -5.25f, 0.f, 1.f}
};
constexpr float AT[4][8] = {
  {1.f, 1.f, 1.f, 1.f, 1.f, 8.f, 8.f, 0.f},
  {0.f, 1.f, -1.f, 2.f, -2.f, 4.f, -4.f, 0.f},
  {0.f, 1.f, 1.f, 4.f, 4.f, 2.f, 2.f, 0.f},
  {0.f, 1.f, -1.f, 8.f, -8.f, 1.f, -1.f, 1.f}
};

__device__ __forceinline__ float bf2f(unsigned short u) {
  union { unsigned int i; float f; } v; v.i = ((unsigned int)u) << 16; return v.f;
}
__device__ __forceinline__ unsigned short f2bf(float f) {
  union { float f; unsigned int i; } v; v.f = f;
  unsigned int r = v.i + 0x7FFFu + ((v.i >> 16) & 1u);  // RNE
  return (unsigned short)(r >> 16);
}

typedef __attribute__((ext_vector_type(8))) short short8;
typedef __attribute__((ext_vector_type(4))) float f32x4;

// ---------------- K1: input transform ----------------
// grid (cg=8, th=16, n=8), block 256 = (tw 16) x (cl 16).
// LDS-stage x[n][c0..c0+15][th*4 .. th*4+7][0..67]; write xt[ab][m][c] bf16.
#define K1_CB 16
#define K1_PS 548   // plane stride in floats: 8*68 + 4 pad (16B aligned, bank-offset 4)
__global__ __launch_bounds__(256) void k_input_tf(const float* __restrict__ x,
                                                  unsigned short* __restrict__ xt) {
  const int cg = blockIdx.x, th = blockIdx.y, n = blockIdx.z;
  const int c0 = cg * K1_CB;
  const int h0 = th * 4;
  __shared__ float xs[K1_CB * K1_PS];

  const int tid = threadIdx.x;
  // cooperative load: 16c * 8r * 17 float4 = 2176 float4
  for (int idx = tid; idx < K1_CB * 8 * 17; idx += 256) {
    const int ci = idx / 136;           // 8*17
    const int rem = idx - ci * 136;
    const int r = rem / 17;
    const int f = rem - r * 17;
    const float4 v = *reinterpret_cast<const float4*>(
        x + ((size_t)((n * IC_ + c0 + ci) * HW_ + h0 + r)) * HW_ + f * 4);
    *reinterpret_cast<float4*>(&xs[ci * K1_PS + r * 68 + f * 4]) = v;
  }
  __syncthreads();

  const int cl = tid & 15;     // channel lane (fast -> coalesced writes)
  const int tw = tid >> 4;
  const float* xp = &xs[cl * K1_PS];

  float t1[8][8];
#pragma unroll
  for (int a = 0; a < 8; ++a)
#pragma unroll
    for (int j = 0; j < 8; ++j) t1[a][j] = 0.f;

#pragma unroll
  for (int i = 0; i < 8; ++i) {
    const float4 v0 = *reinterpret_cast<const float4*>(xp + i * 68 + tw * 4);
    const float4 v1 = *reinterpret_cast<const float4*>(xp + i * 68 + tw * 4 + 4);
    const float r[8] = {v0.x, v0.y, v0.z, v0.w, v1.x, v1.y, v1.z, v1.w};
#pragma unroll
    for (int a = 0; a < 8; ++a) {
      const float ba = BT[a][i];
      if (ba != 0.f) {
#pragma unroll
        for (int j = 0; j < 8; ++j) t1[a][j] += ba * r[j];
      }
    }
  }

  const int m = n * 256 + th * 16 + tw;
  const size_t base = (size_t)m * 128 + c0 + cl;
#pragma unroll
  for (int a = 0; a < 8; ++a) {
#pragma unroll
    for (int b = 0; b < 8; ++b) {
      float v = 0.f;
#pragma unroll
      for (int j = 0; j < 8; ++j) {
        const float bb = BT[b][j];
        if (bb != 0.f) v += t1[a][j] * bb;
      }
      xt[(size_t)(a * 8 + b) * (M_ * 128) + base] = f2bf(v);
    }
  }
}

// ---------------- K2: weight transform to bf16 B^T ----------------
// wT[ab][oc][c] = bf16(w[oc][c][ab])
__global__ __launch_bounds__(256) void k_wt(const float* __restrict__ w,
                                            unsigned short* __restrict__ wT) {
  const int idx = blockIdx.x * 256 + threadIdx.x;  // 64*128*128
  const int c  = idx & 127;
  const int oc = (idx >> 7) & 127;
  const int ab = idx >> 14;
  wT[idx] = f2bf(w[((size_t)oc * IC_ + c) * 64 + ab]);
}

// ---------------- K3: batched MFMA GEMM ----------------
// per ab: C[m][oc] = sum_c A[m][c] * Bt[oc][c];  A,Bt,C bf16 (f32 accum)
// BM=64 (grid.x=32), BN=128 (full OC), K=128 fully staged. 256 thr = 4 waves (2x2).
// LDS XOR-swizzle (chunk ^= row&7) applied via pre-swizzled global source.
__global__ __launch_bounds__(256) void k_gemm(const unsigned short* __restrict__ xt,
                                              const unsigned short* __restrict__ wT,
                                              unsigned short* __restrict__ yt) {
  const int ab = blockIdx.z;
  const int m0 = blockIdx.x * 64;
  const unsigned short* Ag = xt + (size_t)ab * (M_ * 128);
  const unsigned short* Bg = wT + (size_t)ab * (128 * 128);
  unsigned short* Cg = yt + (size_t)ab * (M_ * 128);

  __shared__ unsigned short As[64 * 128];    // 16 KB, row=m, 16 chunks of 16B
  __shared__ unsigned short Bs[128 * 128];   // 32 KB, row=oc

  const int tid = threadIdx.x;
  const int lane = tid & 63;
  const int wv = tid >> 6;

  // ---- stage A (16 wave-insts total, 4 per wave), B (32, 8 per wave) ----
#pragma unroll
  for (int i = 0; i < 4; ++i) {
    const int inst = wv * 4 + i;
    const int r = inst * 4 + (lane >> 4);
    const int j = (lane & 15) ^ (r & 7);
    __builtin_amdgcn_global_load_lds(
        (const __attribute__((address_space(1))) void*)(Ag + (size_t)(m0 + r) * 128 + j * 8),
        (__attribute__((address_space(3))) void*)(As + inst * 512), 16, 0, 0);
  }
#pragma unroll
  for (int i = 0; i < 8; ++i) {
    const int inst = wv * 8 + i;
    const int r = inst * 4 + (lane >> 4);
    const int j = (lane & 15) ^ (r & 7);
    __builtin_amdgcn_global_load_lds(
        (const __attribute__((address_space(1))) void*)(Bg + (size_t)r * 128 + j * 8),
        (__attribute__((address_space(3))) void*)(Bs + inst * 512), 16, 0, 0);
  }
  __syncthreads();

  // ---- compute: wave (wm, wn): 32m x 64oc ----
  const int wm = wv >> 1, wn = wv & 1;
  const int m_base = wm * 32;
  const int oc_base = wn * 64;
  const int lr = lane & 15;
  const int lg = lane >> 4;

  f32x4 acc[2][4];
#pragma unroll
  for (int mi = 0; mi < 2; ++mi)
#pragma unroll
    for (int ni = 0; ni < 4; ++ni) acc[mi][ni] = (f32x4){0.f, 0.f, 0.f, 0.f};

#pragma unroll
  for (int kk = 0; kk < 4; ++kk) {
    short8 af[2], bf[4];
#pragma unroll
    for (int mi = 0; mi < 2; ++mi) {
      const int row = m_base + mi * 16 + lr;
      const int chunk = (kk * 4 + lg) ^ (row & 7);
      af[mi] = *reinterpret_cast<const short8*>(&As[row * 128 + chunk * 8]);
    }
#pragma unroll
    for (int ni = 0; ni < 4; ++ni) {
      const int row = oc_base + ni * 16 + lr;
      const int chunk = (kk * 4 + lg) ^ (row & 7);
      bf[ni] = *reinterpret_cast<const short8*>(&Bs[row * 128 + chunk * 8]);
    }
#pragma unroll
    for (int mi = 0; mi < 2; ++mi)
#pragma unroll
      for (int ni = 0; ni < 4; ++ni)
        acc[mi][ni] = __builtin_amdgcn_mfma_f32_16x16x32_bf16(af[mi], bf[ni], acc[mi][ni], 0, 0, 0);
  }

  // ---- epilogue: C[row][col], col=lane&15, row=(lane>>4)*4+reg ----
#pragma unroll
  for (int mi = 0; mi < 2; ++mi) {
#pragma unroll
    for (int ni = 0; ni < 4; ++ni) {
#pragma unroll
      for (int j = 0; j < 4; ++j) {
        const int row = m0 + m_base + mi * 16 + lg * 4 + j;
        const int col = oc_base + ni * 16 + lr;
        Cg[(size_t)row * 128 + col] = f2bf(acc[mi][ni][j]);
      }
    }
  }
}

// ---------------- K4: output transform + bias ----------------
// grid (og=4, th=16, n=8), block 512 = (tw 16) x (ocl 32).
// read yt[ab][m][oc] (oc-coalesced), transform, LDS-stage, row-coalesced y write.
#define K4_PS 260   // per-oc plane stride in floats: 4*64 + 4 pad
__global__ __launch_bounds__(512) void k_output_tf(const unsigned short* __restrict__ yt,
                                                   const float* __restrict__ bias,
                                                   float* __restrict__ y) {
  const int og = blockIdx.x, th = blockIdx.y, n = blockIdx.z;
  const int oc0 = og * 32;
  const int tid = threadIdx.x;
  const int ocl = tid & 31;
  const int tw = tid >> 5;
  const int m = n * 256 + th * 16 + tw;

  __shared__ float ys[32 * K4_PS];

  float Y[8][8];
  const size_t rb = (size_t)m * 128 + oc0 + ocl;
#pragma unroll
  for (int a = 0; a < 8; ++a)
#pragma unroll
    for (int b = 0; b < 8; ++b)
      Y[a][b] = bf2f(yt[(size_t)(a * 8 + b) * (M_ * 128) + rb]);

  float t2[4][8];
#pragma unroll
  for (int p = 0; p < 4; ++p)
#pragma unroll
    for (int b = 0; b < 8; ++b) {
      float v = 0.f;
#pragma unroll
      for (int a = 0; a < 8; ++a) {
        const float aa = AT[p][a];
        if (aa != 0.f) v += aa * Y[a][b];
      }
      t2[p][b] = v;
    }

  const float bv = bias[oc0 + ocl];
#pragma unroll
  for (int p = 0; p < 4; ++p) {
    float o[4];
#pragma unroll
    for (int q = 0; q < 4; ++q) {
      float v = 0.f;
#pragma unroll
      for (int b = 0; b < 8; ++b) {
        const float ab_ = AT[q][b];
        if (ab_ != 0.f) v += t2[p][b] * ab_;
      }
      o[q] = v + bv;
    }
    const float4 ov = {o[0], o[1], o[2], o[3]};
    *reinterpret_cast<float4*>(&ys[ocl * K4_PS + p * 64 + tw * 4]) = ov;
  }
  __syncthreads();

  // cooperative write-out: 32 oc * 4 rows * 16 float4 = 2048 float4
#pragma unroll
  for (int it = 0; it < 4; ++it) {
    const int idx = it * 512 + tid;
    const int f = idx & 15;
    const int p = (idx >> 4) & 3;
    const int oo = idx >> 6;
    const float4 v = *reinterpret_cast<const float4*>(&ys[oo * K4_PS + p * 64 + f * 4]);
    *reinterpret_cast<float4*>(
        y + ((size_t)((n * OC_ + oc0 + oo) * OW_) + th * 4 + p) * OW_ + f * 4) = v;
  }
}

// ---------------- launch ----------------
extern "C" void kernel_launch(void* const* d_in, const int* in_sizes, int n_in,
                              void* d_out, int out_size, void* d_ws, size_t ws_size,
                              hipStream_t stream) {
  (void)in_sizes; (void)n_in; (void)out_size; (void)ws_size;
  const float* x    = (const float*)d_in[0];
  const float* w    = (const float*)d_in[1];
  const float* bias = (const float*)d_in[2];
  float* y = (float*)d_out;

  char* ws = (char*)d_ws;
  unsigned short* xt = (unsigned short*)ws;                                 // 32 MiB
  unsigned short* yt = (unsigned short*)(ws + (size_t)32 * 1024 * 1024);    // 32 MiB
  unsigned short* wT = (unsigned short*)(ws + (size_t)64 * 1024 * 1024);    //  2 MiB

  hipLaunchKernelGGL(k_input_tf, dim3(8, 16, 8), dim3(256), 0, stream, x, xt);
  hipLaunchKernelGGL(k_wt, dim3((64 * 128 * 128) / 256), dim3(256), 0, stream, w, wT);
  hipLaunchKernelGGL(k_gemm, dim3(32, 1, 64), dim3(256), 0, stream, xt, wT, yt);
  hipLaunchKernelGGL(k_output_tf, dim3(4, 16, 8), dim3(512), 0, stream, yt, bias, y);
}